// Round 7
// baseline (232.950 us; speedup 1.0000x reference)
//
#include <hip/hip_runtime.h>
#include <math.h>

typedef __bf16 bf16;
typedef __attribute__((ext_vector_type(8))) __bf16 bf16x8;
typedef __attribute__((ext_vector_type(4))) __bf16 bf16x4;
typedef __attribute__((ext_vector_type(4))) float f32x4;

#define B_  2
#define S_  2048
#define H_  1024
#define NH_ 16
#define D_  64

__device__ __forceinline__ f32x4 mfma16(bf16x8 a, bf16x8 b, f32x4 c) {
    return __builtin_amdgcn_mfma_f32_16x16x32_bf16(a, b, c, 0, 0, 0);
}

// async global->LDS, 16B per lane; lds dest = wave-uniform base + lane*16
__device__ __forceinline__ void async16(void* lds, const void* g) {
    __builtin_amdgcn_global_load_lds(
        (const __attribute__((address_space(1))) unsigned int*)g,
        (__attribute__((address_space(3))) unsigned int*)lds, 16, 0, 0);
}

// Merged prep: cvt x -> xb, cvt Wqkv -> wqb, build RoPE table tab[s][i]={cos,sin}
__global__ __launch_bounds__(256) void cvt_main(
    const float* __restrict__ x, const float* __restrict__ wqkv,
    bf16* __restrict__ xb, bf16* __restrict__ wqb, float2* __restrict__ tab)
{
    const int bid = blockIdx.x, tid = threadIdx.x;
    if (bid < 4096) {
        int i = bid * 256 + tid;
        f32x4 v = *(const f32x4*)(x + (size_t)i * 4);
        bf16x4 o; o[0]=(bf16)v[0]; o[1]=(bf16)v[1]; o[2]=(bf16)v[2]; o[3]=(bf16)v[3];
        *(bf16x4*)(xb + (size_t)i * 4) = o;
    } else if (bid < 7168) {
        int i = (bid - 4096) * 256 + tid;
        f32x4 v = *(const f32x4*)(wqkv + (size_t)i * 4);
        bf16x4 o; o[0]=(bf16)v[0]; o[1]=(bf16)v[1]; o[2]=(bf16)v[2]; o[3]=(bf16)v[3];
        *(bf16x4*)(wqb + (size_t)i * 4) = o;
    } else {
        int idx = (bid - 7168) * 256 + tid;      // idx = s*32 + i
        int s = idx >> 5, i = idx & 31;
        float f = exp2f((float)i * (-13.287712379549449f / 32.0f));
        float sn, cs;
        sincosf((float)s * f, &sn, &cs);
        tab[idx] = make_float2(cs, sn);
    }
}

// C[M,N] = A[M,K] @ W[N,K]^T, BK=64 K-tiles, classic 2-barrier m97 loop (R5
// structure: the measured local optimum; dbuf/single-barrier regressed, R6).
// LDS rows 64 elems (8 chunks of 16B), XOR-swizzled: phys = logical ^ (row&7)
// -> 0 bank conflicts (measured R5).
// EPI=0 (NT=128): A,W bf16 via global_load_lds; fused RMSNorm + table-RoPE
//   epilogue (q/k), lambda-mix packed transposed store (v).
// EPI=1 (NT=64): W staged from fp32 in-kernel (register preload pipelined
//   across the compute phase, cvt + swizzled ds_write_b128); fp32 out.
template <int EPI, int NT>
__global__ __launch_bounds__(256) void gemm_bt(
    const bf16* __restrict__ A, const bf16* __restrict__ W,
    const float* __restrict__ Wf,
    int M, int N, int K,
    float* __restrict__ outF,
    bf16* __restrict__ qb, bf16* __restrict__ kb, bf16* __restrict__ vtb,
    const float* __restrict__ ve, const float* __restrict__ lambdas,
    const float2* __restrict__ tab)
{
    constexpr int JN = NT / 32;            // n-subtiles per wave
    __shared__ bf16 Al[128][64];
    __shared__ bf16 Bl[NT][64];
    const int m0   = blockIdx.y * 128;
    const int n0   = blockIdx.x * NT;
    const int tid  = threadIdx.x;
    const int lane = tid & 63;
    const int w    = tid >> 6;
    const int quad = lane >> 4;
    const int l16  = lane & 15;
    const int wm   = (w >> 1) * 64;
    const int wn   = (w & 1) * (NT / 2);
    const int r8   = lane >> 3;                 // row within 8-row group
    const int cs   = ((lane & 7) ^ r8) * 8;     // swizzled source col (elems)
    // fp32-W manual staging geometry (EPI=1): row tr, chunk pair c2
    const int tr   = tid >> 2;                  // 0..63
    const int c2   = (tid & 3) * 2;             // logical chunks c2, c2+1

    const f32x4 Z4 = {0.f, 0.f, 0.f, 0.f};
    f32x4 acc[4][JN];
#pragma unroll
    for (int i = 0; i < 4; ++i)
#pragma unroll
        for (int j = 0; j < JN; ++j) acc[i][j] = Z4;

    f32x4 wreg[4];
    if constexpr (EPI == 1) {
        const float* src = Wf + (size_t)(n0 + tr) * K + c2 * 8;
        wreg[0] = *(const f32x4*)(src);
        wreg[1] = *(const f32x4*)(src + 4);
        wreg[2] = *(const f32x4*)(src + 8);
        wreg[3] = *(const f32x4*)(src + 12);
    }

    const int niter = K >> 6;
    for (int it = 0; it < niter; ++it) {
        const int k0 = it << 6;
        {   // A tile: wave w stages rows [w*32, w*32+32)
            const bf16* gA = A + (size_t)(m0 + w * 32 + r8) * K + k0 + cs;
            async16(&Al[w * 32][0],      gA);
            async16(&Al[w * 32 + 8][0],  gA + (size_t)8  * K);
            async16(&Al[w * 32 + 16][0], gA + (size_t)16 * K);
            async16(&Al[w * 32 + 24][0], gA + (size_t)24 * K);
        }
        if constexpr (EPI == 0) {
            const bf16* gB = W + (size_t)(n0 + w * 32 + r8) * K + k0 + cs;
            async16(&Bl[w * 32][0],      gB);
            async16(&Bl[w * 32 + 8][0],  gB + (size_t)8  * K);
            async16(&Bl[w * 32 + 16][0], gB + (size_t)16 * K);
            async16(&Bl[w * 32 + 24][0], gB + (size_t)24 * K);
        } else {
            bf16x8 v0, v1;
#pragma unroll
            for (int q = 0; q < 4; ++q) {
                v0[q] = (bf16)wreg[0][q]; v0[4 + q] = (bf16)wreg[1][q];
                v1[q] = (bf16)wreg[2][q]; v1[4 + q] = (bf16)wreg[3][q];
            }
            *(bf16x8*)&Bl[tr][(c2 ^ (tr & 7)) * 8]       = v0;
            *(bf16x8*)&Bl[tr][((c2 + 1) ^ (tr & 7)) * 8] = v1;
        }
        __syncthreads();
        if constexpr (EPI == 1) {
            if (it + 1 < niter) {     // preload next W tile; latency hidden by compute
                const float* src = Wf + (size_t)(n0 + tr) * K + k0 + 64 + c2 * 8;
                wreg[0] = *(const f32x4*)(src);
                wreg[1] = *(const f32x4*)(src + 4);
                wreg[2] = *(const f32x4*)(src + 8);
                wreg[3] = *(const f32x4*)(src + 12);
            }
        }
#pragma unroll
        for (int ks = 0; ks < 2; ++ks) {
            bf16x8 af[4], bfg[JN];
#pragma unroll
            for (int i = 0; i < 4; ++i)
                af[i] = *(const bf16x8*)
                    &Al[wm + i * 16 + l16][(((ks << 2) + quad) ^ (l16 & 7)) * 8];
#pragma unroll
            for (int j = 0; j < JN; ++j)
                bfg[j] = *(const bf16x8*)
                    &Bl[wn + j * 16 + l16][(((ks << 2) + quad) ^ (l16 & 7)) * 8];
#pragma unroll
            for (int i = 0; i < 4; ++i)
#pragma unroll
                for (int j = 0; j < JN; ++j)
                    acc[i][j] = mfma16(af[i], bfg[j], acc[i][j]);
        }
        __syncthreads();
    }

    if constexpr (EPI == 1) {
#pragma unroll
        for (int i = 0; i < 4; ++i)
#pragma unroll
            for (int j = 0; j < JN; ++j)
#pragma unroll
                for (int r = 0; r < 4; ++r) {
                    int m = m0 + wm + i * 16 + quad * 4 + r;
                    int n = n0 + wn + j * 16 + l16;
                    outF[(size_t)m * N + n] = acc[i][j][r];
                }
    } else {
        const int nbase = n0 + wn;              // wave-uniform
        const int which = nbase >> 10;          // 0=q 1=k 2=v
        const int h     = (nbase & (H_ - 1)) >> 6;
        if (which < 2) {
            bf16* dst = which ? kb : qb;
#pragma unroll
            for (int i = 0; i < 4; ++i) {
                float ss[4];
#pragma unroll
                for (int r = 0; r < 4; ++r)
                    ss[r] = acc[i][0][r] * acc[i][0][r] + acc[i][1][r] * acc[i][1][r]
                          + acc[i][2][r] * acc[i][2][r] + acc[i][3][r] * acc[i][3][r];
#pragma unroll
                for (int r = 0; r < 4; ++r) {
                    ss[r] += __shfl_xor(ss[r], 1);
                    ss[r] += __shfl_xor(ss[r], 2);
                    ss[r] += __shfl_xor(ss[r], 4);
                    ss[r] += __shfl_xor(ss[r], 8);
                }
#pragma unroll
                for (int r = 0; r < 4; ++r) {
                    int    m   = m0 + wm + i * 16 + quad * 4 + r;
                    int    bb  = m >> 11, s = m & (S_ - 1);
                    float  rms = rsqrtf(ss[r] * (1.0f / 64.0f) + 1.1920929e-07f);
                    float  x0 = acc[i][0][r] * rms, x1 = acc[i][1][r] * rms;
                    float  x2 = acc[i][2][r] * rms, x3 = acc[i][3][r] * rms;
                    float2 t0 = tab[(size_t)s * 32 + l16];        // {cos,sin} i=l16
                    float2 t1 = tab[(size_t)s * 32 + 16 + l16];   // i=l16+16
                    bf16*  bp = dst + ((size_t)(bb * NH_ + h) * S_ + s) * D_;
                    bp[l16]      = (bf16)(x0 * t0.x + x2 * t0.y);
                    bp[16 + l16] = (bf16)(x1 * t1.x + x3 * t1.y);
                    bp[32 + l16] = (bf16)(x2 * t0.x - x0 * t0.y);
                    bp[48 + l16] = (bf16)(x3 * t1.x - x1 * t1.y);
                }
            }
        } else {
            const float l0 = lambdas[0], l1 = lambdas[1];
#pragma unroll
            for (int i = 0; i < 4; ++i) {
                const int m00 = m0 + wm + i * 16 + quad * 4;   // 4 consecutive s
                const int bb  = m00 >> 11, s = m00 & (S_ - 1);
#pragma unroll
                for (int j = 0; j < 4; ++j) {
                    const int d = j * 16 + l16;
                    bf16x4 pk;
#pragma unroll
                    for (int r = 0; r < 4; ++r) {
                        float vm = l0 * acc[i][j][r]
                                 + l1 * ve[(size_t)(m00 + r) * H_ + h * 64 + d];
                        pk[r] = (bf16)vm;
                    }
                    *(bf16x4*)&vtb[((size_t)(bb * NH_ + h) * D_ + d) * S_ + s] = pk;
                }
            }
        }
    }
}

// Flash attention, 128-query tiles: each wave owns 2 q-subtiles of 16 rows, so
// every staged 64-key chunk feeds 32 MFMA (2x the old density; staging bytes and
// barrier count halved). Pairing {bx, 15-bx} -> exactly 34 chunk-slots per block;
// grid (8, B*NH) = 256 blocks = 1/CU, perfectly balanced. Static max=8,
// swapped-operand QK, dbuf K/V via global_load_lds, diagonal-limited masking;
// in a tile's last chunk the low subtile is fully masked -> skipped.
__global__ __launch_bounds__(256) void attn(
    const bf16* __restrict__ Q, const bf16* __restrict__ Kg,
    const bf16* __restrict__ Vt, bf16* __restrict__ Og)
{
    __shared__ bf16 Kl[2][64][64];
    __shared__ bf16 Vl[2][64][64];
    __shared__ bf16 Pl[4][16][64];

    const int bh   = blockIdx.y;
    const int b    = bh >> 4;
    const int h    = bh & 15;
    const int tid  = threadIdx.x;
    const int lane = tid & 63;
    const int w    = tid >> 6;
    const int quad = lane >> 4;
    const int l16  = lane & 15;
    const int l7   = l16 & 7;

    const bf16* Qp = Q  + (size_t)bh * S_ * D_;
    const bf16* Kp = Kg + (size_t)bh * S_ * D_;
    const bf16* Vp = Vt + (size_t)bh * D_ * S_;

    const int srow = lane >> 3;
    const int schk = (lane & 7) ^ (lane >> 3);
    const f32x4 Z4 = {0.f, 0.f, 0.f, 0.f};
    const float C1 = 0.18033688011112042f;     // 0.125*log2(e)
    const float C2 = -11.541560327111707f;     // -8*log2(e)

    auto stage = [&](int p, int kb0) {
        const bf16* gK = Kp + (size_t)(kb0 + w * 16 + srow) * D_ + schk * 8;
        async16(&Kl[p][w * 16][0], gK);
        async16(&Kl[p][w * 16 + 8][0], gK + (size_t)8 * D_);
        const bf16* gV = Vp + (size_t)(w * 16 + srow) * S_ + kb0 + schk * 8;
        async16(&Vl[p][w * 16][0], gV);
        async16(&Vl[p][w * 16 + 8][0], gV + (size_t)8 * S_);
    };

    for (int half = 0; half < 2; ++half) {
        const int qt    = half ? (15 - blockIdx.x) : blockIdx.x;   // 128-q tile id
        const int qbase = qt * 128;

        bf16x8 qf[2][2];
        int    qi[2];
#pragma unroll
        for (int qs = 0; qs < 2; ++qs) {
            int qr = qbase + qs * 64 + w * 16 + l16;
            qi[qs] = qr;
            qf[qs][0] = *(const bf16x8*)(Qp + (size_t)qr * D_ + quad * 8);
            qf[qs][1] = *(const bf16x8*)(Qp + (size_t)qr * D_ + 32 + quad * 8);
        }

        f32x4 of[2][4];
#pragma unroll
        for (int qs = 0; qs < 2; ++qs)
#pragma unroll
            for (int dt = 0; dt < 4; ++dt) of[qs][dt] = Z4;
        float lsum[2] = {0.f, 0.f};

        const int nch = 2 * qt + 2;
        __syncthreads();           // prev half's compute done before restaging buf0
        stage(0, 0);
        for (int c = 0; c < nch; ++c) {
            const int p   = c & 1;
            const int kb0 = c * 64;
            __syncthreads();                 // buf[p] ready (prefetch aged 1 phase)
            if (c + 1 < nch) stage(p ^ 1, kb0 + 64);

#pragma unroll
            for (int qs = 0; qs < 2; ++qs) {
                if (qs == 0 && c == 2 * qt + 1) continue;   // fully masked
                const int klim = (c == 2 * qt + qs) ? qi[qs] : 0x7fffffff;
                float ps = 0.f;
#pragma unroll
                for (int nt = 0; nt < 4; ++nt) {
                    bf16x8 kf0 = *(const bf16x8*)&Kl[p][nt * 16 + l16][(quad ^ l7) * 8];
                    bf16x8 kf1 = *(const bf16x8*)&Kl[p][nt * 16 + l16][((quad + 4) ^ l7) * 8];
                    f32x4 sacc = Z4;
                    sacc = mfma16(kf0, qf[qs][0], sacc);
                    sacc = mfma16(kf1, qf[qs][1], sacc);
                    bf16x4 pk;
#pragma unroll
                    for (int r = 0; r < 4; ++r) {
                        int   key = kb0 + nt * 16 + quad * 4 + r;
                        float pv  = (key <= klim) ? exp2f(fmaf(sacc[r], C1, C2)) : 0.f;
                        ps += pv;
                        pk[r] = (bf16)pv;
                    }
                    *(bf16x4*)&Pl[w][l16][((nt * 2 + (quad >> 1)) ^ l7) * 8 + (quad & 1) * 4] = pk;
                }
                ps += __shfl_xor(ps, 16);
                ps += __shfl_xor(ps, 32);
                lsum[qs] += ps;

                bf16x8 pf0 = *(const bf16x8*)&Pl[w][l16][(quad ^ l7) * 8];
                bf16x8 pf1 = *(const bf16x8*)&Pl[w][l16][((quad + 4) ^ l7) * 8];
#pragma unroll
                for (int dt = 0; dt < 4; ++dt) {
                    bf16x8 vf0 = *(const bf16x8*)&Vl[p][dt * 16 + l16][(quad ^ l7) * 8];
                    bf16x8 vf1 = *(const bf16x8*)&Vl[p][dt * 16 + l16][((quad + 4) ^ l7) * 8];
                    of[qs][dt] = mfma16(pf0, vf0, of[qs][dt]);
                    of[qs][dt] = mfma16(pf1, vf1, of[qs][dt]);
                }
            }
        }

#pragma unroll
        for (int qs = 0; qs < 2; ++qs)
#pragma unroll
            for (int r = 0; r < 4; ++r) {
                float ld = __shfl(lsum[qs], quad * 4 + r);
                float rl = 1.0f / ld;
                int   qq = qbase + qs * 64 + w * 16 + quad * 4 + r;
#pragma unroll
                for (int dt = 0; dt < 4; ++dt)
                    Og[((size_t)(b * S_ + qq)) * H_ + h * D_ + dt * 16 + l16] =
                        (bf16)(of[qs][dt][r] * rl);
            }
    }
}

extern "C" void kernel_launch(void* const* d_in, const int* in_sizes, int n_in,
                              void* d_out, int out_size, void* d_ws, size_t ws_size,
                              hipStream_t stream)
{
    const float* x       = (const float*)d_in[0];
    const float* ve      = (const float*)d_in[1];
    const float* Wqkv    = (const float*)d_in[2];
    const float* Wo      = (const float*)d_in[3];
    const float* lambdas = (const float*)d_in[4];
    float* out = (float*)d_out;

    // d_out (16 MiB) early-phase scratch: xb [0,8M), wqb [8,14M), rope tab [14,14.5M).
    // All die after gemm1; gemm2 overwrites d_out with the final output (W_o is
    // staged from fp32 inside gemm2).
    // ws (32 MiB): qb [0,8M), kb [8,16M), vtb [16,24M), ao [24,32M).
    char* od = (char*)d_out;
    char* ws = (char*)d_ws;
    const size_t MB = 1024 * 1024;
    bf16*   xb  = (bf16*)(od);
    bf16*   wqb = (bf16*)(od + 8 * MB);
    float2* tab = (float2*)(od + 14 * MB);
    bf16*   qb  = (bf16*)(ws);
    bf16*   kb  = (bf16*)(ws + 8 * MB);
    bf16*   vtb = (bf16*)(ws + 16 * MB);
    bf16*   ao  = (bf16*)(ws + 24 * MB);

    // 1) convert x + W_qkv to bf16, build RoPE table (one kernel)
    cvt_main<<<7424, 256, 0, stream>>>(x, Wqkv, xb, wqb, tab);
    // 2) qkv GEMM (BK=64, 2-barrier), fused RMSNorm+RoPE / lambda-mix epilogue
    gemm_bt<0, 128><<<dim3(24, 32), 256, 0, stream>>>(
        xb, wqb, nullptr, B_ * S_, 3 * H_, H_, nullptr, qb, kb, vtb, ve, lambdas,
        (const float2*)tab);
    // 3) balanced 128-q-tile causal flash attention -> ao
    attn<<<dim3(8, B_ * NH_), 256, 0, stream>>>(qb, kb, vtb, ao);
    // 4) out = ao @ Wo^T (BK=64, fp32 W_o staged in-kernel, fp32 out)
    gemm_bt<1, 64><<<dim3(16, 32), 256, 0, stream>>>(
        ao, nullptr, Wo, B_ * S_, H_, H_, out, nullptr, nullptr, nullptr,
        nullptr, nullptr, nullptr);
}

// Round 8
// 217.174 us; speedup vs baseline: 1.0726x; 1.0726x over previous
//
#include <hip/hip_runtime.h>
#include <math.h>

typedef __bf16 bf16;
typedef __attribute__((ext_vector_type(8))) __bf16 bf16x8;
typedef __attribute__((ext_vector_type(4))) __bf16 bf16x4;
typedef __attribute__((ext_vector_type(4))) float f32x4;

#define B_  2
#define S_  2048
#define H_  1024
#define NH_ 16
#define D_  64

__device__ __forceinline__ f32x4 mfma16(bf16x8 a, bf16x8 b, f32x4 c) {
    return __builtin_amdgcn_mfma_f32_16x16x32_bf16(a, b, c, 0, 0, 0);
}

// async global->LDS, 16B per lane; lds dest = wave-uniform base + lane*16
__device__ __forceinline__ void async16(void* lds, const void* g) {
    __builtin_amdgcn_global_load_lds(
        (const __attribute__((address_space(1))) unsigned int*)g,
        (__attribute__((address_space(3))) unsigned int*)lds, 16, 0, 0);
}

// Merged prep: cvt x -> xb, cvt Wqkv -> wqb, build RoPE table tab[s][i]={cos,sin}
__global__ __launch_bounds__(256) void cvt_main(
    const float* __restrict__ x, const float* __restrict__ wqkv,
    bf16* __restrict__ xb, bf16* __restrict__ wqb, float2* __restrict__ tab)
{
    const int bid = blockIdx.x, tid = threadIdx.x;
    if (bid < 4096) {
        int i = bid * 256 + tid;
        f32x4 v = *(const f32x4*)(x + (size_t)i * 4);
        bf16x4 o; o[0]=(bf16)v[0]; o[1]=(bf16)v[1]; o[2]=(bf16)v[2]; o[3]=(bf16)v[3];
        *(bf16x4*)(xb + (size_t)i * 4) = o;
    } else if (bid < 7168) {
        int i = (bid - 4096) * 256 + tid;
        f32x4 v = *(const f32x4*)(wqkv + (size_t)i * 4);
        bf16x4 o; o[0]=(bf16)v[0]; o[1]=(bf16)v[1]; o[2]=(bf16)v[2]; o[3]=(bf16)v[3];
        *(bf16x4*)(wqb + (size_t)i * 4) = o;
    } else {
        int idx = (bid - 7168) * 256 + tid;      // idx = s*32 + i
        int s = idx >> 5, i = idx & 31;
        float f = exp2f((float)i * (-13.287712379549449f / 32.0f));
        float sn, cs;
        sincosf((float)s * f, &sn, &cs);
        tab[idx] = make_float2(cs, sn);
    }
}

// fp32 -> bf16 bulk convert (W_o), 4 elems/thread
__global__ __launch_bounds__(256) void cvt_bf16(const float* __restrict__ src,
                                                bf16* __restrict__ dst, int n4) {
    int i = blockIdx.x * 256 + threadIdx.x;
    if (i >= n4) return;
    f32x4 v = *(const f32x4*)(src + (size_t)i * 4);
    bf16x4 o; o[0]=(bf16)v[0]; o[1]=(bf16)v[1]; o[2]=(bf16)v[2]; o[3]=(bf16)v[3];
    *(bf16x4*)(dst + (size_t)i * 4) = o;
}

// C[M,N] = A[M,K] @ W[N,K]^T, bf16, BK=64 K-tiles, 2-barrier m97 loop (R5: the
// measured local optimum). LDS rows 64 elems (8 chunks of 16B), XOR-swizzled:
// phys = logical ^ (row&7) -> 0 bank conflicts (measured R5).
// EPI=0 (NT=128, qkv): fused RMSNorm + table-RoPE for q/k; lambda-mix + packed
//   transposed store for v. EPI=1: plain fp32 store.
template <int EPI, int NT>
__global__ __launch_bounds__(256) void gemm_bt(
    const bf16* __restrict__ A, const bf16* __restrict__ W,
    int M, int N, int K,
    float* __restrict__ outF,
    bf16* __restrict__ qb, bf16* __restrict__ kb, bf16* __restrict__ vtb,
    const float* __restrict__ ve, const float* __restrict__ lambdas,
    const float2* __restrict__ tab)
{
    constexpr int JN = NT / 32;            // n-subtiles per wave
    __shared__ bf16 Al[128][64];
    __shared__ bf16 Bl[NT][64];
    const int m0   = blockIdx.y * 128;
    const int n0   = blockIdx.x * NT;
    const int tid  = threadIdx.x;
    const int lane = tid & 63;
    const int w    = tid >> 6;
    const int quad = lane >> 4;
    const int l16  = lane & 15;
    const int wm   = (w >> 1) * 64;
    const int wn   = (w & 1) * (NT / 2);
    const int r8   = lane >> 3;                 // row within 8-row group
    const int cs   = ((lane & 7) ^ r8) * 8;     // swizzled source col (elems)

    const f32x4 Z4 = {0.f, 0.f, 0.f, 0.f};
    f32x4 acc[4][JN];
#pragma unroll
    for (int i = 0; i < 4; ++i)
#pragma unroll
        for (int j = 0; j < JN; ++j) acc[i][j] = Z4;

    for (int k0 = 0; k0 < K; k0 += 64) {
        {   // A tile: wave w stages rows [w*32, w*32+32)
            const bf16* gA = A + (size_t)(m0 + w * 32 + r8) * K + k0 + cs;
            async16(&Al[w * 32][0],      gA);
            async16(&Al[w * 32 + 8][0],  gA + (size_t)8  * K);
            async16(&Al[w * 32 + 16][0], gA + (size_t)16 * K);
            async16(&Al[w * 32 + 24][0], gA + (size_t)24 * K);
        }
        if constexpr (NT == 128) {
            const bf16* gB = W + (size_t)(n0 + w * 32 + r8) * K + k0 + cs;
            async16(&Bl[w * 32][0],      gB);
            async16(&Bl[w * 32 + 8][0],  gB + (size_t)8  * K);
            async16(&Bl[w * 32 + 16][0], gB + (size_t)16 * K);
            async16(&Bl[w * 32 + 24][0], gB + (size_t)24 * K);
        } else {
            const bf16* gB = W + (size_t)(n0 + w * 16 + r8) * K + k0 + cs;
            async16(&Bl[w * 16][0],     gB);
            async16(&Bl[w * 16 + 8][0], gB + (size_t)8 * K);
        }
        __syncthreads();
#pragma unroll
        for (int ks = 0; ks < 2; ++ks) {
            bf16x8 af[4], bfg[JN];
#pragma unroll
            for (int i = 0; i < 4; ++i)
                af[i] = *(const bf16x8*)
                    &Al[wm + i * 16 + l16][(((ks << 2) + quad) ^ (l16 & 7)) * 8];
#pragma unroll
            for (int j = 0; j < JN; ++j)
                bfg[j] = *(const bf16x8*)
                    &Bl[wn + j * 16 + l16][(((ks << 2) + quad) ^ (l16 & 7)) * 8];
#pragma unroll
            for (int i = 0; i < 4; ++i)
#pragma unroll
                for (int j = 0; j < JN; ++j)
                    acc[i][j] = mfma16(af[i], bfg[j], acc[i][j]);
        }
        __syncthreads();
    }

    if constexpr (EPI == 1) {
#pragma unroll
        for (int i = 0; i < 4; ++i)
#pragma unroll
            for (int j = 0; j < JN; ++j)
#pragma unroll
                for (int r = 0; r < 4; ++r) {
                    int m = m0 + wm + i * 16 + quad * 4 + r;
                    int n = n0 + wn + j * 16 + l16;
                    outF[(size_t)m * N + n] = acc[i][j][r];
                }
    } else {
        const int nbase = n0 + wn;              // wave-uniform
        const int which = nbase >> 10;          // 0=q 1=k 2=v
        const int h     = (nbase & (H_ - 1)) >> 6;
        if (which < 2) {
            bf16* dst = which ? kb : qb;
#pragma unroll
            for (int i = 0; i < 4; ++i) {
                float ss[4];
#pragma unroll
                for (int r = 0; r < 4; ++r)
                    ss[r] = acc[i][0][r] * acc[i][0][r] + acc[i][1][r] * acc[i][1][r]
                          + acc[i][2][r] * acc[i][2][r] + acc[i][3][r] * acc[i][3][r];
#pragma unroll
                for (int r = 0; r < 4; ++r) {
                    ss[r] += __shfl_xor(ss[r], 1);
                    ss[r] += __shfl_xor(ss[r], 2);
                    ss[r] += __shfl_xor(ss[r], 4);
                    ss[r] += __shfl_xor(ss[r], 8);
                }
#pragma unroll
                for (int r = 0; r < 4; ++r) {
                    int    m   = m0 + wm + i * 16 + quad * 4 + r;
                    int    bb  = m >> 11, s = m & (S_ - 1);
                    float  rms = rsqrtf(ss[r] * (1.0f / 64.0f) + 1.1920929e-07f);
                    float  x0 = acc[i][0][r] * rms, x1 = acc[i][1][r] * rms;
                    float  x2 = acc[i][2][r] * rms, x3 = acc[i][3][r] * rms;
                    float2 t0 = tab[(size_t)s * 32 + l16];        // {cos,sin} i=l16
                    float2 t1 = tab[(size_t)s * 32 + 16 + l16];   // i=l16+16
                    bf16*  bp = dst + ((size_t)(bb * NH_ + h) * S_ + s) * D_;
                    bp[l16]      = (bf16)(x0 * t0.x + x2 * t0.y);
                    bp[16 + l16] = (bf16)(x1 * t1.x + x3 * t1.y);
                    bp[32 + l16] = (bf16)(x2 * t0.x - x0 * t0.y);
                    bp[48 + l16] = (bf16)(x3 * t1.x - x1 * t1.y);
                }
            }
        } else {
            const float l0 = lambdas[0], l1 = lambdas[1];
#pragma unroll
            for (int i = 0; i < 4; ++i) {
                const int m00 = m0 + wm + i * 16 + quad * 4;   // 4 consecutive s
                const int bb  = m00 >> 11, s = m00 & (S_ - 1);
#pragma unroll
                for (int j = 0; j < 4; ++j) {
                    const int d = j * 16 + l16;
                    bf16x4 pk;
#pragma unroll
                    for (int r = 0; r < 4; ++r) {
                        float vm = l0 * acc[i][j][r]
                                 + l1 * ve[(size_t)(m00 + r) * H_ + h * 64 + d];
                        pk[r] = (bf16)vm;
                    }
                    *(bf16x4*)&vtb[((size_t)(bb * NH_ + h) * D_ + d) * S_ + s] = pk;
                }
            }
        }
    }
}

// Flash attention with 2-way K-split (flash-decoding style). Static max=8 makes
// partials ADDITIVE (no rescale): O = sum of split partials, l = sum of split
// row-sums. Grid (16, 2, B*NH) = 1024 blocks = 4/CU (LDS 40KB). Block (bx,sz)
// handles q-tiles {bx, 31-bx}, key-chunk half sz of each -> uniform 16-17
// chunks/block. Writes un-normalized bf16 partial O + fp32 partial row-sums.
__global__ __launch_bounds__(256) void attn(
    const bf16* __restrict__ Q, const bf16* __restrict__ Kg,
    const bf16* __restrict__ Vt, bf16* __restrict__ opart,
    float* __restrict__ lsumg)
{
    __shared__ bf16 Kl[2][64][64];
    __shared__ bf16 Vl[2][64][64];
    __shared__ bf16 Pl[4][16][64];

    const int sz   = blockIdx.y;               // key-split half
    const int bh   = blockIdx.z;
    const int b    = bh >> 4;
    const int h    = bh & 15;
    const int tid  = threadIdx.x;
    const int lane = tid & 63;
    const int w    = tid >> 6;
    const int quad = lane >> 4;
    const int l16  = lane & 15;
    const int l7   = l16 & 7;

    const bf16* Qp = Q  + (size_t)bh * S_ * D_;
    const bf16* Kp = Kg + (size_t)bh * S_ * D_;
    const bf16* Vp = Vt + (size_t)bh * D_ * S_;
    bf16*  op = opart + (size_t)sz * (B_ * S_ * H_);
    float* lp = lsumg + sz * (B_ * NH_ * S_);

    const int srow = lane >> 3;
    const int schk = (lane & 7) ^ (lane >> 3);
    const f32x4 Z4 = {0.f, 0.f, 0.f, 0.f};
    const float C1 = 0.18033688011112042f;     // 0.125*log2(e)
    const float C2 = -11.541560327111707f;     // -8*log2(e)

    auto stage = [&](int p, int kb0) {
        const bf16* gK = Kp + (size_t)(kb0 + w * 16 + srow) * D_ + schk * 8;
        async16(&Kl[p][w * 16][0], gK);
        async16(&Kl[p][w * 16 + 8][0], gK + (size_t)8 * D_);
        const bf16* gV = Vp + (size_t)(w * 16 + srow) * S_ + kb0 + schk * 8;
        async16(&Vl[p][w * 16][0], gV);
        async16(&Vl[p][w * 16 + 8][0], gV + (size_t)8 * S_);
    };

    for (int half = 0; half < 2; ++half) {
        const int qt    = half ? (31 - blockIdx.x) : blockIdx.x;
        const int qbase = qt * 64 + w * 16;
        const int qi    = qbase + l16;
        const int nt    = qt + 1;                 // total chunks for this tile
        const int h0    = (nt + 1) >> 1;          // split point
        const int c0    = sz ? h0 : 0;
        const int c1    = sz ? nt : h0;

        bf16x8 qf0 = *(const bf16x8*)(Qp + (size_t)(qbase + l16) * D_ + quad * 8);
        bf16x8 qf1 = *(const bf16x8*)(Qp + (size_t)(qbase + l16) * D_ + 32 + quad * 8);

        f32x4 of[4];
#pragma unroll
        for (int dt = 0; dt < 4; ++dt) of[dt] = Z4;
        float lsum = 0.f;

        if (c0 < c1) {                 // block-uniform branch
            __syncthreads();           // prev half's compute done before restaging buf0
            stage(0, c0 * 64);
            for (int c = c0; c < c1; ++c) {
                const int p   = (c - c0) & 1;
                const int kb0 = c * 64;
                __syncthreads();       // buf[p] ready (prefetch aged 1 phase)
                if (c + 1 < c1) stage(p ^ 1, kb0 + 64);

                const int klim = (c == nt - 1) ? qi : 0x7fffffff;
                float ps = 0.f;
#pragma unroll
                for (int ntl = 0; ntl < 4; ++ntl) {
                    bf16x8 kf0 = *(const bf16x8*)&Kl[p][ntl * 16 + l16][(quad ^ l7) * 8];
                    bf16x8 kf1 = *(const bf16x8*)&Kl[p][ntl * 16 + l16][((quad + 4) ^ l7) * 8];
                    f32x4 sacc = Z4;
                    sacc = mfma16(kf0, qf0, sacc);
                    sacc = mfma16(kf1, qf1, sacc);
                    bf16x4 pk;
#pragma unroll
                    for (int r = 0; r < 4; ++r) {
                        int   key = kb0 + ntl * 16 + quad * 4 + r;
                        float pv  = (key <= klim) ? exp2f(fmaf(sacc[r], C1, C2)) : 0.f;
                        ps += pv;
                        pk[r] = (bf16)pv;
                    }
                    *(bf16x4*)&Pl[w][l16][((ntl * 2 + (quad >> 1)) ^ l7) * 8 + (quad & 1) * 4] = pk;
                }
                ps += __shfl_xor(ps, 16);
                ps += __shfl_xor(ps, 32);
                lsum += ps;

                bf16x8 pf0 = *(const bf16x8*)&Pl[w][l16][(quad ^ l7) * 8];
                bf16x8 pf1 = *(const bf16x8*)&Pl[w][l16][((quad + 4) ^ l7) * 8];
#pragma unroll
                for (int dt = 0; dt < 4; ++dt) {
                    bf16x8 vf0 = *(const bf16x8*)&Vl[p][dt * 16 + l16][(quad ^ l7) * 8];
                    bf16x8 vf1 = *(const bf16x8*)&Vl[p][dt * 16 + l16][((quad + 4) ^ l7) * 8];
                    of[dt] = mfma16(pf0, vf0, of[dt]);
                    of[dt] = mfma16(pf1, vf1, of[dt]);
                }
            }
        }

        // write un-normalized partial O (bf16) + partial row-sum (fp32)
#pragma unroll
        for (int r = 0; r < 4; ++r) {
            int qq = qbase + quad * 4 + r;
#pragma unroll
            for (int dt = 0; dt < 4; ++dt)
                op[((size_t)(b * S_ + qq)) * H_ + h * D_ + dt * 16 + l16] =
                    (bf16)of[dt][r];
        }
        if (lane < 16)
            lp[bh * S_ + qbase + lane] = lsum;
    }
}

// Combine: ao = (Op0 + Op1) / (l0 + l1), 8 elems/thread
__global__ __launch_bounds__(256) void combine(
    const bf16* __restrict__ opart, const float* __restrict__ lsumg,
    bf16* __restrict__ ao)
{
    const int i  = blockIdx.x * 256 + threadIdx.x;
    const int e0 = i * 8;
    const int bb = e0 >> 21;                 // / (S*H)
    const int s  = (e0 >> 10) & (S_ - 1);
    const int h  = (e0 & (H_ - 1)) >> 6;
    const int bh = bb * NH_ + h;
    float l = lsumg[bh * S_ + s] + lsumg[B_ * NH_ * S_ + bh * S_ + s];
    float rl = 1.0f / l;
    bf16x8 a = *(const bf16x8*)(opart + e0);
    bf16x8 c = *(const bf16x8*)(opart + (size_t)(B_ * S_ * H_) + e0);
    bf16x8 o;
#pragma unroll
    for (int j = 0; j < 8; ++j)
        o[j] = (bf16)(((float)a[j] + (float)c[j]) * rl);
    *(bf16x8*)(ao + e0) = o;
}

extern "C" void kernel_launch(void* const* d_in, const int* in_sizes, int n_in,
                              void* d_out, int out_size, void* d_ws, size_t ws_size,
                              hipStream_t stream)
{
    const float* x       = (const float*)d_in[0];
    const float* ve      = (const float*)d_in[1];
    const float* Wqkv    = (const float*)d_in[2];
    const float* Wo      = (const float*)d_in[3];
    const float* lambdas = (const float*)d_in[4];
    float* out = (float*)d_out;

    // d_out (16 MiB): phase 1 scratch xb[0,8M) wqb[8,14M) tab[14,14.5M) (die
    // after gemm1); phase 2: attn bf16 partials Opart[2] = [0,8M),[8,16M);
    // phase 3: gemm2 overwrites with final fp32 output.
    // ws (32 MiB): qb[0,8M) kb[8,16M) vtb[16,24M) lsum[24,24.5M) wob[24.5,26.5M);
    // combine writes ao over retired qb [0,8M).
    char* od = (char*)d_out;
    char* ws = (char*)d_ws;
    const size_t MB = 1024 * 1024;
    bf16*   xb    = (bf16*)(od);
    bf16*   wqb   = (bf16*)(od + 8 * MB);
    float2* tab   = (float2*)(od + 14 * MB);
    bf16*   opart = (bf16*)(od);
    bf16*   qb    = (bf16*)(ws);
    bf16*   kb    = (bf16*)(ws + 8 * MB);
    bf16*   vtb   = (bf16*)(ws + 16 * MB);
    float*  lsum  = (float*)(ws + 24 * MB);
    bf16*   wob   = (bf16*)(ws + 24 * MB + 512 * 1024);
    bf16*   ao    = (bf16*)(ws);

    // 1) convert x + W_qkv to bf16, build RoPE table
    cvt_main<<<7424, 256, 0, stream>>>(x, Wqkv, xb, wqb, tab);
    // 2) qkv GEMM (BK=64, 2-barrier), fused RMSNorm+RoPE / lambda-mix epilogue
    gemm_bt<0, 128><<<dim3(24, 32), 256, 0, stream>>>(
        xb, wqb, B_ * S_, 3 * H_, H_, nullptr, qb, kb, vtb, ve, lambdas,
        (const float2*)tab);
    // 3) K-split balanced causal flash attention -> bf16 partials + row-sums
    attn<<<dim3(16, 2, B_ * NH_), 256, 0, stream>>>(qb, kb, vtb, opart, lsum);
    // 4) combine partials -> ao (over retired qb)
    combine<<<(B_ * S_ * H_) / (256 * 8), 256, 0, stream>>>(opart, lsum, ao);
    // 5) convert W_o
    cvt_bf16<<<1024, 256, 0, stream>>>(Wo, wob, (H_ * H_) / 4);
    // 6) out = ao @ Wo^T (fp32, overwrites d_out)
    gemm_bt<1, 64><<<dim3(16, 32), 256, 0, stream>>>(
        ao, wob, B_ * S_, H_, H_, out, nullptr, nullptr, nullptr,
        nullptr, nullptr, nullptr);
}